// Round 2
// baseline (168.119 us; speedup 1.0000x reference)
//
#include <hip/hip_runtime.h>

#define GRID_D 128
#define NSITES (GRID_D * GRID_D)   // 16384
#define HID 64
#define BATCH 64
#define SPB 256                    // sites per block
#define BPB (NSITES / SPB)         // 64 blocks per batch

// One thread = one (batch, site). Weights are wave-uniform -> scalar loads.
// h2[64] accumulators live in VGPRs; h1 computed one element at a time (fused).
__global__ __launch_bounds__(256)
void gauge_fused(const float* __restrict__ x,
                 const float* __restrict__ H,
                 const float* __restrict__ W_emb,
                 const float* __restrict__ b_emb,
                 const float* __restrict__ W_hid,
                 const float* __restrict__ b_hid,
                 const float* __restrict__ W_post,
                 const float* __restrict__ b_post,
                 float* __restrict__ out)
{
    const int bid   = blockIdx.x;
    const int b     = bid / BPB;
    const int chunk = bid % BPB;
    const int i     = chunk * SPB + threadIdx.x;

    // 2x2 gauge matrix (uniform -> SGPRs)
    const float h00 = H[0], h01 = H[1], h10 = H[2], h11 = H[3];

    const float* __restrict__ xb = x + (size_t)b * NSITES * 2;

    // torus neighbors (NBR order: up, down, left, right)
    const int xc = i & (GRID_D - 1);
    const int yc = i >> 7;
    const int n0 = xc + (((yc + 1) & (GRID_D - 1)) << 7);           // up
    const int n1 = xc + (((yc - 1) & (GRID_D - 1)) << 7);           // down
    const int n2 = ((xc - 1) & (GRID_D - 1)) + (yc << 7);           // left
    const int n3 = ((xc + 1) & (GRID_D - 1)) + (yc << 7);           // right

    const float2 xi  = *(const float2*)(xb + 2 * i);
    const float2 xu  = *(const float2*)(xb + 2 * n0);
    const float2 xd  = *(const float2*)(xb + 2 * n1);
    const float2 xl  = *(const float2*)(xb + 2 * n2);
    const float2 xr  = *(const float2*)(xb + 2 * n3);

    // s[k] = x_i^T H x_nbr(k)
    float s0 = xi.x * fmaf(h00, xu.x, h01 * xu.y) + xi.y * fmaf(h10, xu.x, h11 * xu.y);
    float s1 = xi.x * fmaf(h00, xd.x, h01 * xd.y) + xi.y * fmaf(h10, xd.x, h11 * xd.y);
    float s2 = xi.x * fmaf(h00, xl.x, h01 * xl.y) + xi.y * fmaf(h10, xl.x, h11 * xl.y);
    float s3 = xi.x * fmaf(h00, xr.x, h01 * xr.y) + xi.y * fmaf(h10, xr.x, h11 * xr.y);

    // hidden-layer accumulators
    float h2[HID];
    #pragma unroll
    for (int j = 0; j < HID; ++j) h2[j] = b_hid[j];

    // fused: h1_l = relu(emb), then rank-1 update into h2
    #pragma unroll 16
    for (int l = 0; l < HID; ++l) {
        float h1 = b_emb[l];
        h1 = fmaf(s0, W_emb[0 * HID + l], h1);
        h1 = fmaf(s1, W_emb[1 * HID + l], h1);
        h1 = fmaf(s2, W_emb[2 * HID + l], h1);
        h1 = fmaf(s3, W_emb[3 * HID + l], h1);
        h1 = fmaxf(h1, 0.0f);
        #pragma unroll
        for (int j = 0; j < HID; ++j)
            h2[j] = fmaf(h1, W_hid[l * HID + j], h2[j]);
    }

    // post layer + site output
    float o = b_post[0];
    #pragma unroll
    for (int j = 0; j < HID; ++j)
        o = fmaf(fmaxf(h2[j], 0.0f), W_post[j], o);

    // block reduction (all sites in this block share batch b)
    #pragma unroll
    for (int off = 32; off > 0; off >>= 1)
        o += __shfl_down(o, off, 64);

    __shared__ float partial[SPB / 64];
    const int lane = threadIdx.x & 63;
    const int wv   = threadIdx.x >> 6;
    if (lane == 0) partial[wv] = o;
    __syncthreads();
    if (threadIdx.x == 0) {
        float t = 0.0f;
        #pragma unroll
        for (int w = 0; w < SPB / 64; ++w) t += partial[w];
        atomicAdd(&out[b], t);
    }
}

extern "C" void kernel_launch(void* const* d_in, const int* in_sizes, int n_in,
                              void* d_out, int out_size, void* d_ws, size_t ws_size,
                              hipStream_t stream)
{
    const float* x      = (const float*)d_in[0];
    const float* H      = (const float*)d_in[1];
    const float* W_emb  = (const float*)d_in[2];
    const float* b_emb  = (const float*)d_in[3];
    const float* W_hid  = (const float*)d_in[4];
    const float* b_hid  = (const float*)d_in[5];
    const float* W_post = (const float*)d_in[6];
    const float* b_post = (const float*)d_in[7];
    float* out = (float*)d_out;

    // harness poisons d_out with 0xAA; we accumulate with atomics -> zero it
    hipMemsetAsync(out, 0, (size_t)out_size * sizeof(float), stream);

    dim3 grid(BATCH * BPB);   // 4096 blocks
    dim3 block(SPB);          // 256 threads
    gauge_fused<<<grid, block, 0, stream>>>(x, H, W_emb, b_emb, W_hid, b_hid,
                                            W_post, b_post, out);
}

// Round 3
// 103.279 us; speedup vs baseline: 1.6278x; 1.6278x over previous
//
#include <hip/hip_runtime.h>
#include <hip/hip_bf16.h>

#define GRID_D 128
#define NSITES (GRID_D * GRID_D)   // 16384
#define HID 64
#define BATCH 64

#define WPB 4                       // waves per block
#define BLOCKS 2048
#define WAVES_TOTAL (BLOCKS * WPB)              // 8192
#define WAVES_PER_BATCH (WAVES_TOTAL / BATCH)   // 128
#define TILES_PER_WAVE (NSITES / (WAVES_PER_BATCH * 16))  // 8
#define SITES_PER_BLOCK (WPB * TILES_PER_WAVE * 16)       // 512

typedef short bf16x8 __attribute__((ext_vector_type(8)));
typedef float f32x4  __attribute__((ext_vector_type(4)));

__device__ __forceinline__ unsigned short f2bf(float f) {
    return __builtin_bit_cast(unsigned short, __float2bfloat16(f));
}

// Per 16-site tile: lane l serves site l%16; k-group (l>>4) covers k=(l>>4)*8..+7
// of each K=32 step. Hidden layer = 8 MFMAs (2 K-steps x 4 N-tiles of 16).
// Output is a full site-sum, so C is consumed as sum(relu(C[:,n])*W_post[n]) --
// no transpose, no LDS in the main loop.
__global__ __launch_bounds__(256)
void gauge_mfma(const float* __restrict__ x,
                const float* __restrict__ H,
                const float* __restrict__ W_emb,
                const float* __restrict__ b_emb,
                const float* __restrict__ W_hid,
                const float* __restrict__ b_hid,
                const float* __restrict__ W_post,
                const float* __restrict__ b_post,
                float* __restrict__ out)
{
    const int tid   = threadIdx.x;
    const int lane  = tid & 63;
    const int widx  = tid >> 6;
    const int wgid  = blockIdx.x * WPB + widx;
    const int b     = wgid / WAVES_PER_BATCH;
    const int wslot = wgid % WAVES_PER_BATCH;

    const int ls = lane & 15;   // site-in-tile (A row) == n-in-tile (B/C col)
    const int kl = (lane >> 4) * 8;   // k-chunk base within a K=32 step

    const float h00 = H[0], h01 = H[1], h10 = H[2], h11 = H[3];

    // ---- loop-invariant B fragments: B[k][n] = W_hid[k*64+n], k=s*32+kl+i, n=t*16+ls
    bf16x8 bfrag[4][2];
    #pragma unroll
    for (int t = 0; t < 4; ++t) {
        #pragma unroll
        for (int s = 0; s < 2; ++s) {
            union { bf16x8 v; unsigned short us[8]; } r;
            #pragma unroll
            for (int i = 0; i < 8; ++i)
                r.us[i] = f2bf(W_hid[(s * 32 + kl + i) * HID + t * 16 + ls]);
            bfrag[t][s] = r.v;
        }
    }

    // per-lane bias / post-weight for each N-tile (col = t*16+ls)
    float bh[4], wp[4];
    #pragma unroll
    for (int t = 0; t < 4; ++t) {
        bh[t] = b_hid[t * 16 + ls];
        wp[t] = W_post[t * 16 + ls];
    }

    const float* __restrict__ xb = x + (size_t)b * NSITES * 2;
    float o = 0.0f;

    for (int tile = 0; tile < TILES_PER_WAVE; ++tile) {
        const int site = wslot * (16 * TILES_PER_WAVE) + tile * 16 + ls;
        const int xc = site & (GRID_D - 1);
        const int yc = site >> 7;
        const int n0 = xc + (((yc + 1) & (GRID_D - 1)) << 7);
        const int n1 = xc + (((yc - 1) & (GRID_D - 1)) << 7);
        const int n2 = ((xc - 1) & (GRID_D - 1)) + (yc << 7);
        const int n3 = ((xc + 1) & (GRID_D - 1)) + (yc << 7);

        const float2 xi = *(const float2*)(xb + 2 * site);
        const float2 xu = *(const float2*)(xb + 2 * n0);
        const float2 xd = *(const float2*)(xb + 2 * n1);
        const float2 xl = *(const float2*)(xb + 2 * n2);
        const float2 xr = *(const float2*)(xb + 2 * n3);

        const float s0 = xi.x * fmaf(h00, xu.x, h01 * xu.y) + xi.y * fmaf(h10, xu.x, h11 * xu.y);
        const float s1 = xi.x * fmaf(h00, xd.x, h01 * xd.y) + xi.y * fmaf(h10, xd.x, h11 * xd.y);
        const float s2 = xi.x * fmaf(h00, xl.x, h01 * xl.y) + xi.y * fmaf(h10, xl.x, h11 * xl.y);
        const float s3 = xi.x * fmaf(h00, xr.x, h01 * xr.y) + xi.y * fmaf(h10, xr.x, h11 * xr.y);

        // ---- A fragments: h1[k] = relu(b_emb[k] + sum_m s_m * W_emb[m][k]), k = s*32+kl+i
        bf16x8 afrag[2];
        #pragma unroll
        for (int s = 0; s < 2; ++s) {
            const int kb = s * 32 + kl;
            float hv[8];
            {
                const float4 be0 = *(const float4*)(b_emb + kb);
                const float4 be1 = *(const float4*)(b_emb + kb + 4);
                hv[0] = be0.x; hv[1] = be0.y; hv[2] = be0.z; hv[3] = be0.w;
                hv[4] = be1.x; hv[5] = be1.y; hv[6] = be1.z; hv[7] = be1.w;
            }
            #pragma unroll
            for (int m = 0; m < 4; ++m) {
                const float sm = (m == 0) ? s0 : (m == 1) ? s1 : (m == 2) ? s2 : s3;
                const float4 w0 = *(const float4*)(W_emb + m * HID + kb);
                const float4 w1 = *(const float4*)(W_emb + m * HID + kb + 4);
                hv[0] = fmaf(sm, w0.x, hv[0]); hv[1] = fmaf(sm, w0.y, hv[1]);
                hv[2] = fmaf(sm, w0.z, hv[2]); hv[3] = fmaf(sm, w0.w, hv[3]);
                hv[4] = fmaf(sm, w1.x, hv[4]); hv[5] = fmaf(sm, w1.y, hv[5]);
                hv[6] = fmaf(sm, w1.z, hv[6]); hv[7] = fmaf(sm, w1.w, hv[7]);
            }
            union { bf16x8 v; unsigned short us[8]; } r;
            #pragma unroll
            for (int i = 0; i < 8; ++i)
                r.us[i] = f2bf(fmaxf(hv[i], 0.0f));
            afrag[s] = r.v;
        }

        // ---- hidden layer via MFMA + fused relu/post epilogue
        #pragma unroll
        for (int t = 0; t < 4; ++t) {
            f32x4 acc = { bh[t], bh[t], bh[t], bh[t] };   // bias init
            acc = __builtin_amdgcn_mfma_f32_16x16x32_bf16(afrag[0], bfrag[t][0], acc, 0, 0, 0);
            acc = __builtin_amdgcn_mfma_f32_16x16x32_bf16(afrag[1], bfrag[t][1], acc, 0, 0, 0);
            #pragma unroll
            for (int r = 0; r < 4; ++r)
                o = fmaf(fmaxf(acc[r], 0.0f), wp[t], o);
        }
    }

    // wave reduce, then block reduce, one atomic per block
    #pragma unroll
    for (int off = 32; off > 0; off >>= 1)
        o += __shfl_down(o, off, 64);

    __shared__ float part[WPB];
    if (lane == 0) part[widx] = o;
    __syncthreads();
    if (tid == 0) {
        float t = part[0] + part[1] + part[2] + part[3];
        t += (float)SITES_PER_BLOCK * b_post[0];
        atomicAdd(&out[b], t);
    }
}

extern "C" void kernel_launch(void* const* d_in, const int* in_sizes, int n_in,
                              void* d_out, int out_size, void* d_ws, size_t ws_size,
                              hipStream_t stream)
{
    const float* x      = (const float*)d_in[0];
    const float* H      = (const float*)d_in[1];
    const float* W_emb  = (const float*)d_in[2];
    const float* b_emb  = (const float*)d_in[3];
    const float* W_hid  = (const float*)d_in[4];
    const float* b_hid  = (const float*)d_in[5];
    const float* W_post = (const float*)d_in[6];
    const float* b_post = (const float*)d_in[7];
    float* out = (float*)d_out;

    hipMemsetAsync(out, 0, (size_t)out_size * sizeof(float), stream);

    gauge_mfma<<<dim3(BLOCKS), dim3(256), 0, stream>>>(
        x, H, W_emb, b_emb, W_hid, b_hid, W_post, b_post, out);
}